// Round 4
// baseline (349.700 us; speedup 1.0000x reference)
//
#include <hip/hip_runtime.h>

// ProbabilityMatrixFactorization:
//   rating[u,i] = dot(user_weight[user_ids[u]], item_weight[item_ids[i]])
//              + user_bias[user_ids[u]] + item_bias[item_ids[i]] + bias
// Shapes: BATCH=4096 users x BATCH=4096 items, LATENT=64, fp32 in/out.
//
// Strategy (rounds 0-3, fp32-exact baseline):
//  - 64x64 output tile per 256-thread block; K=64 fits entirely in LDS.
//  - Operand tiles staged TRANSPOSED ([k][row]) so inner loop reads are
//    float4 (ds_read_b128): U-read is a 16-lane broadcast (free), I-read is
//    2-way bank-aliased (free on CDNA4 per m136).
//  - Each thread computes a 4x4 register tile: 16 v_fma_f32 per k.
//  - Epilogue adds biases, stores float4 coalesced.

#define BATCH 4096
#define D     64
#define TILE  64

__global__ __launch_bounds__(256) void pmf_tile_kernel(
    const int*   __restrict__ user_ids,
    const int*   __restrict__ item_ids,
    const float* __restrict__ user_weight,
    const float* __restrict__ item_weight,
    const float* __restrict__ user_bias,
    const float* __restrict__ item_bias,
    const float* __restrict__ bias,
    float*       __restrict__ out)
{
    __shared__ float Ut[D][TILE];   // [k][user-row-in-tile]
    __shared__ float It[D][TILE];   // [k][item-row-in-tile]
    __shared__ float ubs[TILE];
    __shared__ float ibs[TILE];

    const int t  = threadIdx.x;
    const int bx = blockIdx.x;      // item tile index
    const int by = blockIdx.y;      // user tile index

    // ---- stage: each thread owns (row r, quad q); loads 4x float4 per matrix
    const int r = t >> 2;           // 0..63
    const int q = t & 3;            // 0..3
    const int urow = user_ids[by * TILE + r];
    const int irow = item_ids[bx * TILE + r];
    const float* up = user_weight + (size_t)urow * D;
    const float* ip = item_weight + (size_t)irow * D;
    #pragma unroll
    for (int i = 0; i < 4; ++i) {
        const int k0 = q * 4 + i * 16;
        const float4 uv = *(const float4*)(up + k0);
        const float4 iv = *(const float4*)(ip + k0);
        Ut[k0 + 0][r] = uv.x; Ut[k0 + 1][r] = uv.y;
        Ut[k0 + 2][r] = uv.z; Ut[k0 + 3][r] = uv.w;
        It[k0 + 0][r] = iv.x; It[k0 + 1][r] = iv.y;
        It[k0 + 2][r] = iv.z; It[k0 + 3][r] = iv.w;
    }
    if (t < TILE) {
        ubs[t] = user_bias[user_ids[by * TILE + t]];
    } else if (t < 2 * TILE) {
        const int tt = t - TILE;
        ibs[tt] = item_bias[item_ids[bx * TILE + tt]];
    }
    __syncthreads();

    // ---- compute: thread (ty,tx) owns rows ty*4..+3, cols tx*4..+3
    const int tx = t & 15;
    const int ty = t >> 4;

    float acc[4][4] = {{0.f}};
    #pragma unroll 16
    for (int k = 0; k < D; ++k) {
        const float4 u  = *(const float4*)&Ut[k][ty * 4];   // broadcast across 16 lanes
        const float4 iv = *(const float4*)&It[k][tx * 4];   // 2-way alias (free)
        const float uu[4] = {u.x, u.y, u.z, u.w};
        const float ii[4] = {iv.x, iv.y, iv.z, iv.w};
        #pragma unroll
        for (int a = 0; a < 4; ++a)
            #pragma unroll
            for (int b = 0; b < 4; ++b)
                acc[a][b] = fmaf(uu[a], ii[b], acc[a][b]);
    }

    // ---- epilogue: biases + coalesced float4 stores
    const float gb = bias[0];
    #pragma unroll
    for (int a = 0; a < 4; ++a) {
        const int row = by * TILE + ty * 4 + a;
        const float ub = ubs[ty * 4 + a] + gb;
        float4 o;
        o.x = acc[a][0] + ub + ibs[tx * 4 + 0];
        o.y = acc[a][1] + ub + ibs[tx * 4 + 1];
        o.z = acc[a][2] + ub + ibs[tx * 4 + 2];
        o.w = acc[a][3] + ub + ibs[tx * 4 + 3];
        *(float4*)(out + (size_t)row * BATCH + bx * TILE + tx * 4) = o;
    }
}

extern "C" void kernel_launch(void* const* d_in, const int* in_sizes, int n_in,
                              void* d_out, int out_size, void* d_ws, size_t ws_size,
                              hipStream_t stream) {
    const int*   user_ids    = (const int*)  d_in[0];
    const int*   item_ids    = (const int*)  d_in[1];
    const float* user_weight = (const float*)d_in[2];
    const float* item_weight = (const float*)d_in[3];
    const float* user_bias   = (const float*)d_in[4];
    const float* item_bias   = (const float*)d_in[5];
    const float* bias        = (const float*)d_in[6];
    float* out = (float*)d_out;

    dim3 grid(BATCH / TILE, BATCH / TILE);   // 64 x 64 = 4096 blocks
    dim3 block(256);
    pmf_tile_kernel<<<grid, block, 0, stream>>>(
        user_ids, item_ids, user_weight, item_weight,
        user_bias, item_bias, bias, out);
}

// Round 10
// 334.069 us; speedup vs baseline: 1.0468x; 1.0468x over previous
//
#include <hip/hip_runtime.h>

// ProbabilityMatrixFactorization — round 9 (resubmit): bf16-MFMA, store-bound.
//   rating[u,i] = dot(uw[user_ids[u]], iw[item_ids[i]]) + ub + ib + bias
//   4096x4096 out, K=64, fp32 in/out. Round-4 fp32 kernel was LDS-pipe-bound
//   (~41 us LDS floor at 1 B/FLOP). MFMA needs 0.125 B/FLOP -> store-bound.
//
// Layout:
//  - Block = 256 thr (4 waves), 128x128 output tile; grid 32x32.
//  - Stage 128 user + 128 item rows as bf16 in LDS, row padded to 144 B
//    (72 bf16): bank0 = 4*((row+slot)%8) -> reads/writes BW-limited, no
//    extra conflicts (the unpadded 128 B row stride is a 16-way conflict).
//  - Wave w owns a 64x64 quadrant: 4x4 tiles of mfma_f32_16x16x32_bf16,
//    K=64 in two k-halves. A-frag = user row (lane&15), 8 contig k at
//    (lane>>4)*8; B-frag = item row, same pattern (C = A*B^T form).
//  - C/D layout (m89/m91): col = lane&15 (item), row = (lane>>4)*4+reg (user).
//  - Epilogue fuses user_bias + item_bias + bias; scalar dword stores
//    (each 16-lane group = one full 64 B line; store-BW limited regardless).

#define BATCH 4096
#define D     64
#define BM    128
#define BN    128
#define ROWSZ 72          // bf16 elements per LDS row (144 B, mult of 16 B)

typedef __attribute__((ext_vector_type(8))) short bf16x8;
typedef __attribute__((ext_vector_type(4))) float f32x4;

static __device__ __forceinline__ unsigned short f2bf(float x) {
    // round-to-nearest-even f32 -> bf16 (finite inputs)
    unsigned int u = __builtin_bit_cast(unsigned int, x);
    u += 0x7FFFu + ((u >> 16) & 1u);
    return (unsigned short)(u >> 16);
}

__global__ __launch_bounds__(256) void pmf_mfma_kernel(
    const int*   __restrict__ user_ids,
    const int*   __restrict__ item_ids,
    const float* __restrict__ user_weight,
    const float* __restrict__ item_weight,
    const float* __restrict__ user_bias,
    const float* __restrict__ item_bias,
    const float* __restrict__ bias,
    float*       __restrict__ out)
{
    __shared__ __align__(16) unsigned short Ul[BM * ROWSZ];
    __shared__ __align__(16) unsigned short Il[BN * ROWSZ];
    __shared__ float ubs[BM];
    __shared__ float ibs[BN];

    const int t  = threadIdx.x;
    const int bx = blockIdx.x;   // item tile
    const int by = blockIdx.y;   // user tile

    // ---- stage: thread t<128 -> user row t; t>=128 -> item row t-128
    {
        const int  r   = t & 127;
        const bool isU = (t < 128);
        const int  gid = isU ? user_ids[by * BM + r] : item_ids[bx * BN + r];
        const float* src = (isU ? user_weight : item_weight) + (size_t)gid * D;
        unsigned short* dst = (isU ? Ul : Il) + r * ROWSZ;
        #pragma unroll
        for (int c = 0; c < D; c += 8) {
            const float4 a = *(const float4*)(src + c);
            const float4 b = *(const float4*)(src + c + 4);
            union { bf16x8 v; unsigned short u[8]; } pk;
            pk.u[0] = f2bf(a.x); pk.u[1] = f2bf(a.y);
            pk.u[2] = f2bf(a.z); pk.u[3] = f2bf(a.w);
            pk.u[4] = f2bf(b.x); pk.u[5] = f2bf(b.y);
            pk.u[6] = f2bf(b.z); pk.u[7] = f2bf(b.w);
            *(bf16x8*)(dst + c) = pk.v;
        }
        const float bv = isU ? user_bias[gid] : item_bias[gid];
        (isU ? ubs : ibs)[r] = bv;
    }
    __syncthreads();

    // ---- compute: wave w owns 64x64 quadrant (wr = w>>1, wc = w&1)
    const int w    = t >> 6;
    const int lane = t & 63;
    const int lo   = lane & 15;      // frag row-in-tile / output col
    const int hi   = lane >> 4;      // frag k-group / output row-group
    const int wr   = w >> 1;
    const int wc   = w & 1;

    f32x4 acc[4][4];
    #pragma unroll
    for (int m = 0; m < 4; ++m)
        #pragma unroll
        for (int n = 0; n < 4; ++n)
            acc[m][n] = (f32x4){0.f, 0.f, 0.f, 0.f};

    #pragma unroll
    for (int kh = 0; kh < 2; ++kh) {
        const int koff = kh * 32 + hi * 8;       // bf16 elem offset in row
        bf16x8 af[4], bf[4];
        #pragma unroll
        for (int m = 0; m < 4; ++m)
            af[m] = *(const bf16x8*)&Ul[(wr * 64 + m * 16 + lo) * ROWSZ + koff];
        #pragma unroll
        for (int n = 0; n < 4; ++n)
            bf[n] = *(const bf16x8*)&Il[(wc * 64 + n * 16 + lo) * ROWSZ + koff];
        #pragma unroll
        for (int m = 0; m < 4; ++m)
            #pragma unroll
            for (int n = 0; n < 4; ++n)
                acc[m][n] = __builtin_amdgcn_mfma_f32_16x16x32_bf16(
                    af[m], bf[n], acc[m][n], 0, 0, 0);
    }

    // ---- epilogue: biases + stores
    const float gb = bias[0];
    float ib4[4];
    #pragma unroll
    for (int n = 0; n < 4; ++n) ib4[n] = ibs[wc * 64 + n * 16 + lo];

    const int orow0 = by * BM + wr * 64 + hi * 4;   // + m*16 + r
    const int ocol0 = bx * BN + wc * 64 + lo;       // + n*16
    float* op = out + (size_t)orow0 * BATCH + ocol0;

    #pragma unroll
    for (int m = 0; m < 4; ++m) {
        #pragma unroll
        for (int r = 0; r < 4; ++r) {
            const float ub = ubs[wr * 64 + m * 16 + hi * 4 + r] + gb;
            const size_t rowoff = (size_t)(m * 16 + r) * BATCH;
            #pragma unroll
            for (int n = 0; n < 4; ++n)
                op[rowoff + n * 16] = acc[m][n][r] + ub + ib4[n];
        }
    }
}

extern "C" void kernel_launch(void* const* d_in, const int* in_sizes, int n_in,
                              void* d_out, int out_size, void* d_ws, size_t ws_size,
                              hipStream_t stream) {
    const int*   user_ids    = (const int*)  d_in[0];
    const int*   item_ids    = (const int*)  d_in[1];
    const float* user_weight = (const float*)d_in[2];
    const float* item_weight = (const float*)d_in[3];
    const float* user_bias   = (const float*)d_in[4];
    const float* item_bias   = (const float*)d_in[5];
    const float* bias        = (const float*)d_in[6];
    float* out = (float*)d_out;

    dim3 grid(BATCH / BN, BATCH / BM);   // 32 x 32
    dim3 block(256);
    pmf_mfma_kernel<<<grid, block, 0, stream>>>(
        user_ids, item_ids, user_weight, item_weight,
        user_bias, item_bias, bias, out);
}